// Round 1
// baseline (99.800 us; speedup 1.0000x reference)
//
#include <hip/hip_runtime.h>

// WarpMesh: rasterize a jittered 16x16 grid mesh over a 384x384 image,
// barycentric-interp UVs, bilinear sample, first-hit face selection.
//
// Exactness strategy: the inside test (w >= -1e-7 on normalized barycentrics)
// is sign-critical vs the numpy fp32 reference. All products feeding the edge
// functions / area go through an asm rounding barrier so the compiler cannot
// FMA-contract a*b - c*d (numpy rounds each op). Division is IEEE by default.

#define NF_MAX 450
#define WIMG 384
#define HIMG 384

__device__ __forceinline__ float fbar(float r) {
    asm volatile("" : "+v"(r));   // rounding/contraction barrier
    return r;
}
__device__ __forceinline__ float mulb(float a, float b) { return fbar(a * b); }

// Per-face table layout (16 floats):
// [0..5]  v0x v0y v1x v1y v2x v2y   (NDC-normalized vertices)
// [6]     inv_area
// [7]     valid (|area| >= 1e-8 ? 1 : 0)
// [8..13] uv0x uv0y uv1x uv1y uv2x uv2y  (uv_points / (W-1))
// [14,15] pad
__global__ void wm_prep_faces(const float* __restrict__ points,
                              const float* __restrict__ uvp,
                              const int* __restrict__ faces,
                              int nf, float* __restrict__ ftab)
{
    int f = blockIdx.x * blockDim.x + threadIdx.x;
    if (f >= nf) return;

    const float sc = (float)(383.0 / 384.0);  // (W-1)/W rounded to fp32
    int idx[3] = { faces[f*3+0], faces[f*3+1], faces[f*3+2] };

    float v[3][2], uv[3][2];
    #pragma unroll
    for (int k = 0; k < 3; ++k) {
        float px = points[idx[k]*2 + 0];
        float py = points[idx[k]*2 + 1];
        // pn = (p / (W-1) * 2 - 1) * ((W-1)/W), each op rounded separately
        float nx = fbar(fbar(fbar(px / 383.0f) * 2.0f - 1.0f) * sc);
        float ny = fbar(fbar(fbar(py / 383.0f) * 2.0f - 1.0f) * sc);
        v[k][0] = nx; v[k][1] = ny;
        uv[k][0] = fbar(uvp[idx[k]*2 + 0] / 383.0f);
        uv[k][1] = fbar(uvp[idx[k]*2 + 1] / 383.0f);
    }

    // area = (v1x-v0x)*(v2y-v0y) - (v1y-v0y)*(v2x-v0x), no contraction
    float area = fbar(mulb(v[1][0]-v[0][0], v[2][1]-v[0][1])
                    - mulb(v[1][1]-v[0][1], v[2][0]-v[0][0]));
    float denom   = (fabsf(area) < 1e-8f) ? 1.0f : area;
    float inv_area = fbar(1.0f / denom);
    float valid    = (fabsf(area) >= 1e-8f) ? 1.0f : 0.0f;

    float* o = ftab + f * 16;
    o[0]=v[0][0]; o[1]=v[0][1]; o[2]=v[1][0]; o[3]=v[1][1]; o[4]=v[2][0]; o[5]=v[2][1];
    o[6]=inv_area; o[7]=valid;
    o[8]=uv[0][0]; o[9]=uv[0][1]; o[10]=uv[1][0]; o[11]=uv[1][1]; o[12]=uv[2][0]; o[13]=uv[2][1];
    o[14]=0.0f; o[15]=0.0f;
}

__global__ __launch_bounds__(256)
void wm_raster(const float* __restrict__ ftab, int nf,
               const float* __restrict__ img, float* __restrict__ out, int npix)
{
    __shared__ float lds[NF_MAX * 16];
    const int tid = threadIdx.x;

    // cooperative float4 stage of the face table (broadcast-read later)
    const int total = nf * 16;
    for (int i = tid * 4; i < total; i += 256 * 4) {
        *(float4*)&lds[i] = *(const float4*)&ftab[i];
    }
    __syncthreads();

    const int p = blockIdx.x * 256 + tid;
    if (p >= npix) return;

    const int row = p / WIMG;
    const int col = p - row * WIMG;

    // px = 2*(col+0.5)/W - 1 ; py = 2*(row+0.5)/H - 1  (each op rounded)
    const float px = fbar(fbar(2.0f * ((float)col + 0.5f) / 384.0f) - 1.0f);
    const float py = fbar(fbar(2.0f * ((float)row + 0.5f) / 384.0f) - 1.0f);

    int   hitf = -1;
    float b0 = 0.0f, b1 = 0.0f, b2 = 0.0f;

    for (int f = 0; f < nf; ++f) {
        const float* fd = &lds[f * 16];
        const float v0x = fd[0], v0y = fd[1];
        const float v1x = fd[2], v1y = fd[3];
        const float v2x = fd[4], v2y = fd[5];
        const float ia = fd[6], valid = fd[7];

        // edge_fn(a,b) = (bx-ax)*(py-ay) - (by-ay)*(px-ax)
        float e0 = fbar(mulb(v2x - v1x, py - v1y) - mulb(v2y - v1y, px - v1x)); // edge(v1,v2)
        float e1 = fbar(mulb(v0x - v2x, py - v2y) - mulb(v0y - v2y, px - v2x)); // edge(v2,v0)
        float e2 = fbar(mulb(v1x - v0x, py - v0y) - mulb(v1y - v0y, px - v0x)); // edge(v0,v1)

        float w0 = mulb(e0, ia);
        float w1 = mulb(e1, ia);
        float w2 = mulb(e2, ia);

        if (valid != 0.0f && w0 >= -1e-7f && w1 >= -1e-7f && w2 >= -1e-7f) {
            hitf = f; b0 = w0; b1 = w1; b2 = w2;
            break;  // first-index hit == argmax(inside) semantics
        }
    }

    float c0 = 0.0f, c1 = 0.0f, c2 = 0.0f;
    if (hitf >= 0) {
        const float* fd = &lds[hitf * 16];
        float ux = b0 * fd[8]  + b1 * fd[10] + b2 * fd[12];
        float uy = b0 * fd[9]  + b1 * fd[11] + b2 * fd[13];

        float x = fminf(fmaxf(ux * 383.0f, 0.0f), 383.0f);
        float y = fminf(fmaxf(uy * 383.0f, 0.0f), 383.0f);
        int x0 = (int)floorf(x);
        int y0 = (int)floorf(y);
        int x1 = min(x0 + 1, 383);
        int y1 = min(y0 + 1, 383);
        float fx = x - (float)x0;
        float fy = y - (float)y0;

        const float* p00 = &img[(y0 * WIMG + x0) * 3];
        const float* p10 = &img[(y0 * WIMG + x1) * 3];
        const float* p01 = &img[(y1 * WIMG + x0) * 3];
        const float* p11 = &img[(y1 * WIMG + x1) * 3];

        float w00 = (1.0f - fx) * (1.0f - fy);
        float w10 = fx * (1.0f - fy);
        float w01 = (1.0f - fx) * fy;
        float w11 = fx * fy;

        c0 = p00[0]*w00 + p10[0]*w10 + p01[0]*w01 + p11[0]*w11;
        c1 = p00[1]*w00 + p10[1]*w10 + p01[1]*w01 + p11[1]*w11;
        c2 = p00[2]*w00 + p10[2]*w10 + p01[2]*w01 + p11[2]*w11;
    }

    out[p * 3 + 0] = c0;
    out[p * 3 + 1] = c1;
    out[p * 3 + 2] = c2;
}

extern "C" void kernel_launch(void* const* d_in, const int* in_sizes, int n_in,
                              void* d_out, int out_size, void* d_ws, size_t ws_size,
                              hipStream_t stream) {
    const float* points = (const float*)d_in[0];
    const float* uvp    = (const float*)d_in[1];
    const float* img    = (const float*)d_in[2];
    const int*   faces  = (const int*)d_in[3];

    int nf = in_sizes[3] / 3;
    if (nf > NF_MAX) nf = NF_MAX;
    float* ftab = (float*)d_ws;   // nf*16*4 = 28.8 KB

    hipLaunchKernelGGL(wm_prep_faces, dim3((nf + 255) / 256), dim3(256), 0, stream,
                       points, uvp, faces, nf, ftab);

    int npix = out_size / 3;
    hipLaunchKernelGGL(wm_raster, dim3((npix + 255) / 256), dim3(256), 0, stream,
                       ftab, nf, img, (float*)d_out, npix);
}

// Round 2
// 14.939 us; speedup vs baseline: 6.6805x; 6.6805x over previous
//
#include <hip/hip_runtime.h>

// WarpMesh: rasterize a jittered 16x16 grid mesh over a 384x384 image.
// R2: per-tile face culling. One block per 16x16 pixel tile; candidate faces
// (bbox overlap with tile, ascending face order via ballot-compaction) are
// staged to LDS; per-pixel loop runs only over candidates. First hit in
// ascending order == reference argmax(inside) semantics.
//
// Exactness: the inside test (w >= -1e-7 on normalized barycentrics) is
// sign-critical vs the numpy fp32 reference; all products feeding edge
// functions / area go through an asm rounding barrier (no FMA contraction).
// Bbox margin 1e-4 NDC >> max boundary extension from tol + fp32 rounding
// (~7.5e-7 NDC), so culling cannot flip any inside bit.

#define NF_MAX 450
#define NF_CAP 512   // 2 rounds x 256 threads
#define WIMG 384
#define HIMG 384
#define MARGIN 1e-4f

__device__ __forceinline__ float fbar(float r) {
    asm volatile("" : "+v"(r));   // rounding/contraction barrier
    return r;
}
__device__ __forceinline__ float mulb(float a, float b) { return fbar(a * b); }

// Per-face table layout (16 floats):
// [0..5]  v0x v0y v1x v1y v2x v2y   (NDC-normalized vertices)
// [6]     inv_area
// [7]     pad (validity encoded in bbox)
// [8..13] uv0x uv0y uv1x uv1y uv2x uv2y  (uv_points / (W-1))
// [14,15] pad
// Separate bbox array: float4 {xmin, ymin, xmax, ymax}; empty for invalid.
__global__ void wm_prep_faces(const float* __restrict__ points,
                              const float* __restrict__ uvp,
                              const int* __restrict__ faces,
                              int nf, float* __restrict__ ftab,
                              float4* __restrict__ fbox)
{
    int f = blockIdx.x * blockDim.x + threadIdx.x;
    if (f >= nf) return;

    const float sc = (float)(383.0 / 384.0);  // (W-1)/W rounded to fp32
    int idx[3] = { faces[f*3+0], faces[f*3+1], faces[f*3+2] };

    float v[3][2], uv[3][2];
    #pragma unroll
    for (int k = 0; k < 3; ++k) {
        float px = points[idx[k]*2 + 0];
        float py = points[idx[k]*2 + 1];
        // pn = (p / (W-1) * 2 - 1) * ((W-1)/W), each op rounded separately
        float nx = fbar(fbar(fbar(px / 383.0f) * 2.0f - 1.0f) * sc);
        float ny = fbar(fbar(fbar(py / 383.0f) * 2.0f - 1.0f) * sc);
        v[k][0] = nx; v[k][1] = ny;
        uv[k][0] = fbar(uvp[idx[k]*2 + 0] / 383.0f);
        uv[k][1] = fbar(uvp[idx[k]*2 + 1] / 383.0f);
    }

    // area = (v1x-v0x)*(v2y-v0y) - (v1y-v0y)*(v2x-v0x), no contraction
    float area = fbar(mulb(v[1][0]-v[0][0], v[2][1]-v[0][1])
                    - mulb(v[1][1]-v[0][1], v[2][0]-v[0][0]));
    bool  valid    = (fabsf(area) >= 1e-8f);
    float denom    = valid ? area : 1.0f;
    float inv_area = fbar(1.0f / denom);

    float* o = ftab + f * 16;
    o[0]=v[0][0]; o[1]=v[0][1]; o[2]=v[1][0]; o[3]=v[1][1]; o[4]=v[2][0]; o[5]=v[2][1];
    o[6]=inv_area; o[7]=0.0f;
    o[8]=uv[0][0]; o[9]=uv[0][1]; o[10]=uv[1][0]; o[11]=uv[1][1]; o[12]=uv[2][0]; o[13]=uv[2][1];
    o[14]=0.0f; o[15]=0.0f;

    float4 bb;
    if (valid) {
        bb.x = fminf(fminf(v[0][0], v[1][0]), v[2][0]);
        bb.y = fminf(fminf(v[0][1], v[1][1]), v[2][1]);
        bb.z = fmaxf(fmaxf(v[0][0], v[1][0]), v[2][0]);
        bb.w = fmaxf(fmaxf(v[0][1], v[1][1]), v[2][1]);
    } else {
        bb.x = 1e30f; bb.y = 1e30f; bb.z = -1e30f; bb.w = -1e30f;  // empty
    }
    fbox[f] = bb;
}

__global__ __launch_bounds__(256)
void wm_raster(const float* __restrict__ ftab, const float4* __restrict__ fbox,
               int nf, const float* __restrict__ img, float* __restrict__ out)
{
    __shared__ unsigned long long masks[8];     // 512 candidate bits
    __shared__ int   list[NF_MAX];
    __shared__ float flds[NF_MAX * 16];

    const int tid = threadIdx.x;
    const int lx  = tid & 15, ly = tid >> 4;
    const int c0  = blockIdx.x * 16, r0 = blockIdx.y * 16;
    const int col = c0 + lx, row = r0 + ly;

    // tile NDC bounds + margin
    const float tx_lo = 2.0f * ((float)c0 + 0.5f)  / 384.0f - 1.0f - MARGIN;
    const float tx_hi = 2.0f * ((float)c0 + 15.5f) / 384.0f - 1.0f + MARGIN;
    const float ty_lo = 2.0f * ((float)r0 + 0.5f)  / 384.0f - 1.0f - MARGIN;
    const float ty_hi = 2.0f * ((float)r0 + 15.5f) / 384.0f - 1.0f + MARGIN;

    // ---- candidate selection: 2 rounds x 256 threads, ascending face order
    bool pred[2];
    #pragma unroll
    for (int r = 0; r < 2; ++r) {
        int f = r * 256 + tid;
        bool p = false;
        if (f < nf) {
            float4 bb = fbox[f];
            p = (bb.x <= tx_hi) & (bb.z >= tx_lo) & (bb.y <= ty_hi) & (bb.w >= ty_lo);
        }
        pred[r] = p;
        unsigned long long m = __ballot(p);
        if ((tid & 63) == 0) masks[r * 4 + (tid >> 6)] = m;
    }
    __syncthreads();

    int ncand = 0;
    #pragma unroll
    for (int k = 0; k < 8; ++k) ncand += __popcll(masks[k]);

    const int lane = tid & 63;
    const unsigned long long below = (lane == 0) ? 0ULL : ((1ULL << lane) - 1ULL);
    #pragma unroll
    for (int r = 0; r < 2; ++r) {
        if (pred[r]) {
            int w = r * 4 + (tid >> 6);
            int pos = __popcll(masks[w] & below);
            for (int k = 0; k < w; ++k) pos += __popcll(masks[k]);
            list[pos] = r * 256 + tid;
        }
    }
    __syncthreads();

    // ---- stage candidate face records into LDS
    for (int i = tid; i < ncand * 16; i += 256)
        flds[i] = ftab[list[i >> 4] * 16 + (i & 15)];
    __syncthreads();

    // ---- per-pixel raster over candidates (ascending face order)
    const float px = fbar(fbar(2.0f * ((float)col + 0.5f) / 384.0f) - 1.0f);
    const float py = fbar(fbar(2.0f * ((float)row + 0.5f) / 384.0f) - 1.0f);

    int   hiti = -1;
    float b0 = 0.0f, b1 = 0.0f, b2 = 0.0f;

    for (int i = 0; i < ncand; ++i) {
        const float* fd = &flds[i * 16];
        const float v0x = fd[0], v0y = fd[1];
        const float v1x = fd[2], v1y = fd[3];
        const float v2x = fd[4], v2y = fd[5];
        const float ia  = fd[6];

        // edge_fn(a,b) = (bx-ax)*(py-ay) - (by-ay)*(px-ax), no contraction
        float e0 = fbar(mulb(v2x - v1x, py - v1y) - mulb(v2y - v1y, px - v1x));
        float e1 = fbar(mulb(v0x - v2x, py - v2y) - mulb(v0y - v2y, px - v2x));
        float e2 = fbar(mulb(v1x - v0x, py - v0y) - mulb(v1y - v0y, px - v0x));

        float w0 = mulb(e0, ia);
        float w1 = mulb(e1, ia);
        float w2 = mulb(e2, ia);

        if (w0 >= -1e-7f && w1 >= -1e-7f && w2 >= -1e-7f) {
            hiti = i; b0 = w0; b1 = w1; b2 = w2;
            break;  // ascending order -> first hit == argmax(inside)
        }
    }

    float c0f = 0.0f, c1f = 0.0f, c2f = 0.0f;
    if (hiti >= 0) {
        const float* fd = &flds[hiti * 16];
        float ux = b0 * fd[8] + b1 * fd[10] + b2 * fd[12];
        float uy = b0 * fd[9] + b1 * fd[11] + b2 * fd[13];

        float x = fminf(fmaxf(ux * 383.0f, 0.0f), 383.0f);
        float y = fminf(fmaxf(uy * 383.0f, 0.0f), 383.0f);
        int x0 = (int)floorf(x);
        int y0 = (int)floorf(y);
        int x1 = min(x0 + 1, 383);
        int y1 = min(y0 + 1, 383);
        float fx = x - (float)x0;
        float fy = y - (float)y0;

        const float* p00 = &img[(y0 * WIMG + x0) * 3];
        const float* p10 = &img[(y0 * WIMG + x1) * 3];
        const float* p01 = &img[(y1 * WIMG + x0) * 3];
        const float* p11 = &img[(y1 * WIMG + x1) * 3];

        float w00 = (1.0f - fx) * (1.0f - fy);
        float w10 = fx * (1.0f - fy);
        float w01 = (1.0f - fx) * fy;
        float w11 = fx * fy;

        c0f = p00[0]*w00 + p10[0]*w10 + p01[0]*w01 + p11[0]*w11;
        c1f = p00[1]*w00 + p10[1]*w10 + p01[1]*w01 + p11[1]*w11;
        c2f = p00[2]*w00 + p10[2]*w10 + p01[2]*w01 + p11[2]*w11;
    }

    const int p = row * WIMG + col;
    out[p * 3 + 0] = c0f;
    out[p * 3 + 1] = c1f;
    out[p * 3 + 2] = c2f;
}

extern "C" void kernel_launch(void* const* d_in, const int* in_sizes, int n_in,
                              void* d_out, int out_size, void* d_ws, size_t ws_size,
                              hipStream_t stream) {
    const float* points = (const float*)d_in[0];
    const float* uvp    = (const float*)d_in[1];
    const float* img    = (const float*)d_in[2];
    const int*   faces  = (const int*)d_in[3];

    int nf = in_sizes[3] / 3;
    if (nf > NF_MAX) nf = NF_MAX;
    float*  ftab = (float*)d_ws;                    // nf*16*4 = 28.8 KB
    float4* fbox = (float4*)((char*)d_ws + NF_MAX * 16 * sizeof(float));

    hipLaunchKernelGGL(wm_prep_faces, dim3((nf + 255) / 256), dim3(256), 0, stream,
                       points, uvp, faces, nf, ftab, fbox);

    hipLaunchKernelGGL(wm_raster, dim3(WIMG / 16, HIMG / 16), dim3(256), 0, stream,
                       ftab, fbox, nf, img, (float*)d_out);
}

// Round 3
// 12.852 us; speedup vs baseline: 7.7651x; 1.1624x over previous
//
#include <hip/hip_runtime.h>

// WarpMesh R3: single fused kernel. Each block (one 16x16 pixel tile):
//  1. redundantly recomputes all 450 face records (NDC verts, inv_area, UVs,
//     bbox) straight into LDS (~2 faces/thread, L2-broadcast-fed),
//  2. bbox-tests faces against the tile, ballot-compacts survivors in
//     ascending face order (preserves reference argmax/first-hit semantics),
//  3. per-pixel: first-hit scan over ~8-16 candidates, bary UV, bilinear.
//
// Exactness: the inside test (w >= -1e-7 on normalized barycentrics) is
// sign-critical vs the numpy fp32 reference; every product feeding the edge
// functions / area goes through an asm rounding barrier (no FMA contraction),
// divisions are IEEE. Bbox margin 1e-4 NDC >> max boundary extension from
// tol + fp32 rounding (~7.5e-7 NDC), so culling cannot flip any inside bit.

#define NF_MAX 450
#define WIMG 384
#define HIMG 384
#define MARGIN 1e-4f

__device__ __forceinline__ float fbar(float r) {
    asm volatile("" : "+v"(r));   // rounding/contraction barrier
    return r;
}
__device__ __forceinline__ float mulb(float a, float b) { return fbar(a * b); }

// Face record (16 floats): [0..5] v0x v0y v1x v1y v2x v2y, [6] inv_area,
// [7] pad, [8..13] uv0x uv0y uv1x uv1y uv2x uv2y, [14,15] pad (unwritten).
__global__ __launch_bounds__(256)
void wm_fused(const float* __restrict__ points,
              const float* __restrict__ uvp,
              const int*   __restrict__ faces,
              int nf,
              const float* __restrict__ img,
              float* __restrict__ out)
{
    __shared__ float  flds[NF_MAX * 16];
    __shared__ float4 fbbox[NF_MAX];
    __shared__ unsigned long long masks[8];
    __shared__ int    list[NF_MAX];

    const int tid = threadIdx.x;

    // ---- per-block face prep (redundant across blocks; tiny, L2-fed) ----
    const float sc = (float)(383.0 / 384.0);  // (W-1)/W rounded to fp32
    for (int f = tid; f < nf; f += 256) {
        int idx[3] = { faces[f*3+0], faces[f*3+1], faces[f*3+2] };

        float v[3][2], uv[3][2];
        #pragma unroll
        for (int k = 0; k < 3; ++k) {
            float px = points[idx[k]*2 + 0];
            float py = points[idx[k]*2 + 1];
            // pn = (p / (W-1) * 2 - 1) * ((W-1)/W), each op rounded separately
            v[k][0] = fbar(fbar(fbar(px / 383.0f) * 2.0f - 1.0f) * sc);
            v[k][1] = fbar(fbar(fbar(py / 383.0f) * 2.0f - 1.0f) * sc);
            uv[k][0] = fbar(uvp[idx[k]*2 + 0] / 383.0f);
            uv[k][1] = fbar(uvp[idx[k]*2 + 1] / 383.0f);
        }

        // area = (v1x-v0x)*(v2y-v0y) - (v1y-v0y)*(v2x-v0x), no contraction
        float area = fbar(mulb(v[1][0]-v[0][0], v[2][1]-v[0][1])
                        - mulb(v[1][1]-v[0][1], v[2][0]-v[0][0]));
        bool  valid    = (fabsf(area) >= 1e-8f);
        float inv_area = fbar(1.0f / (valid ? area : 1.0f));

        float* o = &flds[f * 16];
        o[0]=v[0][0]; o[1]=v[0][1]; o[2]=v[1][0]; o[3]=v[1][1];
        o[4]=v[2][0]; o[5]=v[2][1]; o[6]=inv_area; o[7]=0.0f;
        o[8]=uv[0][0]; o[9]=uv[0][1]; o[10]=uv[1][0]; o[11]=uv[1][1];
        o[12]=uv[2][0]; o[13]=uv[2][1];

        float4 bb;
        if (valid) {
            bb.x = fminf(fminf(v[0][0], v[1][0]), v[2][0]);
            bb.y = fminf(fminf(v[0][1], v[1][1]), v[2][1]);
            bb.z = fmaxf(fmaxf(v[0][0], v[1][0]), v[2][0]);
            bb.w = fmaxf(fmaxf(v[0][1], v[1][1]), v[2][1]);
        } else {
            bb.x = 1e30f; bb.y = 1e30f; bb.z = -1e30f; bb.w = -1e30f; // empty
        }
        fbbox[f] = bb;
    }
    __syncthreads();

    // ---- candidate selection: bbox vs tile, ascending face order ----
    const int lx = tid & 15, ly = tid >> 4;
    const int c0 = blockIdx.x * 16, r0 = blockIdx.y * 16;
    const int col = c0 + lx, row = r0 + ly;

    const float tx_lo = 2.0f * ((float)c0 + 0.5f)  / 384.0f - 1.0f - MARGIN;
    const float tx_hi = 2.0f * ((float)c0 + 15.5f) / 384.0f - 1.0f + MARGIN;
    const float ty_lo = 2.0f * ((float)r0 + 0.5f)  / 384.0f - 1.0f - MARGIN;
    const float ty_hi = 2.0f * ((float)r0 + 15.5f) / 384.0f - 1.0f + MARGIN;

    bool pred[2];
    #pragma unroll
    for (int r = 0; r < 2; ++r) {
        int f = r * 256 + tid;
        bool p = false;
        if (f < nf) {
            float4 bb = fbbox[f];
            p = (bb.x <= tx_hi) & (bb.z >= tx_lo) & (bb.y <= ty_hi) & (bb.w >= ty_lo);
        }
        pred[r] = p;
        unsigned long long m = __ballot(p);
        if ((tid & 63) == 0) masks[r * 4 + (tid >> 6)] = m;
    }
    __syncthreads();

    int ncand = 0;
    #pragma unroll
    for (int k = 0; k < 8; ++k) ncand += __popcll(masks[k]);

    const int lane = tid & 63;
    const unsigned long long below = (lane == 0) ? 0ULL : ((1ULL << lane) - 1ULL);
    #pragma unroll
    for (int r = 0; r < 2; ++r) {
        if (pred[r]) {
            int w = r * 4 + (tid >> 6);
            int pos = __popcll(masks[w] & below);
            for (int k = 0; k < w; ++k) pos += __popcll(masks[k]);
            list[pos] = r * 256 + tid;
        }
    }
    __syncthreads();

    // ---- per-pixel raster over candidates (ascending face order) ----
    const float px = fbar(fbar(2.0f * ((float)col + 0.5f) / 384.0f) - 1.0f);
    const float py = fbar(fbar(2.0f * ((float)row + 0.5f) / 384.0f) - 1.0f);

    int   hitoff = -1;
    float b0 = 0.0f, b1 = 0.0f, b2 = 0.0f;

    for (int i = 0; i < ncand; ++i) {
        const float* fd = &flds[list[i] * 16];   // broadcast LDS reads
        const float v0x = fd[0], v0y = fd[1];
        const float v1x = fd[2], v1y = fd[3];
        const float v2x = fd[4], v2y = fd[5];
        const float ia  = fd[6];

        // edge_fn(a,b) = (bx-ax)*(py-ay) - (by-ay)*(px-ax), no contraction
        float e0 = fbar(mulb(v2x - v1x, py - v1y) - mulb(v2y - v1y, px - v1x));
        float e1 = fbar(mulb(v0x - v2x, py - v2y) - mulb(v0y - v2y, px - v2x));
        float e2 = fbar(mulb(v1x - v0x, py - v0y) - mulb(v1y - v0y, px - v0x));

        float w0 = mulb(e0, ia);
        float w1 = mulb(e1, ia);
        float w2 = mulb(e2, ia);

        if (w0 >= -1e-7f && w1 >= -1e-7f && w2 >= -1e-7f) {
            hitoff = list[i] * 16; b0 = w0; b1 = w1; b2 = w2;
            break;  // ascending order -> first hit == argmax(inside)
        }
    }

    float c0f = 0.0f, c1f = 0.0f, c2f = 0.0f;
    if (hitoff >= 0) {
        const float* fd = &flds[hitoff];
        float ux = b0 * fd[8] + b1 * fd[10] + b2 * fd[12];
        float uy = b0 * fd[9] + b1 * fd[11] + b2 * fd[13];

        float x = fminf(fmaxf(ux * 383.0f, 0.0f), 383.0f);
        float y = fminf(fmaxf(uy * 383.0f, 0.0f), 383.0f);
        int x0 = (int)floorf(x);
        int y0 = (int)floorf(y);
        int x1 = min(x0 + 1, 383);
        int y1 = min(y0 + 1, 383);
        float fx = x - (float)x0;
        float fy = y - (float)y0;

        const float* p00 = &img[(y0 * WIMG + x0) * 3];
        const float* p10 = &img[(y0 * WIMG + x1) * 3];
        const float* p01 = &img[(y1 * WIMG + x0) * 3];
        const float* p11 = &img[(y1 * WIMG + x1) * 3];

        float w00 = (1.0f - fx) * (1.0f - fy);
        float w10 = fx * (1.0f - fy);
        float w01 = (1.0f - fx) * fy;
        float w11 = fx * fy;

        c0f = p00[0]*w00 + p10[0]*w10 + p01[0]*w01 + p11[0]*w11;
        c1f = p00[1]*w00 + p10[1]*w10 + p01[1]*w01 + p11[1]*w11;
        c2f = p00[2]*w00 + p10[2]*w10 + p01[2]*w01 + p11[2]*w11;
    }

    const int p = row * WIMG + col;
    out[p * 3 + 0] = c0f;
    out[p * 3 + 1] = c1f;
    out[p * 3 + 2] = c2f;
}

extern "C" void kernel_launch(void* const* d_in, const int* in_sizes, int n_in,
                              void* d_out, int out_size, void* d_ws, size_t ws_size,
                              hipStream_t stream) {
    const float* points = (const float*)d_in[0];
    const float* uvp    = (const float*)d_in[1];
    const float* img    = (const float*)d_in[2];
    const int*   faces  = (const int*)d_in[3];

    int nf = in_sizes[3] / 3;
    if (nf > NF_MAX) nf = NF_MAX;

    hipLaunchKernelGGL(wm_fused, dim3(WIMG / 16, HIMG / 16), dim3(256), 0, stream,
                       points, uvp, faces, nf, img, (float*)d_out);
}

// Round 4
// 10.867 us; speedup vs baseline: 9.1839x; 1.1827x over previous
//
#include <hip/hip_runtime.h>

// WarpMesh R4: single fused kernel, vertex-first prep.
// Each block (one 16x16 pixel tile):
//  1. vertex stage: 256 threads normalize the 256 mesh vertices (NDC + UV)
//     into LDS — exactly the reference's per-vertex ops (pn = (p/wh*2-1)*sc,
//     uv = uvp/wh), so bit-identical to per-face recomputation.
//  2. face stage (2 uniform rounds x 256 threads): gather verts from LDS,
//     compute edge setup + inv_area into flds (stride 17, conflict-free),
//     bbox + tile overlap in registers, ballot-compact survivors in
//     ascending face order (preserves reference argmax/first-hit semantics).
//  3. per-pixel: first-hit scan over ~8-16 candidates, bary UV, bilinear.
//
// Exactness: the inside test (w >= -1e-7 on normalized barycentrics) is
// sign-critical vs the numpy fp32 reference; every product feeding the edge
// functions / area goes through an asm rounding barrier (no FMA contraction),
// divisions are IEEE. Bbox margin 1e-4 NDC >> max boundary extension from
// tol + fp32 rounding (~7.5e-7 NDC), so culling cannot flip any inside bit.

#define NF_MAX 450
#define NP_MAX 256
#define WIMG 384
#define HIMG 384
#define MARGIN 1e-4f
#define FSTRIDE 17   // coprime with 32 banks -> conflict-free record stores

__device__ __forceinline__ float fbar(float r) {
    asm volatile("" : "+v"(r));   // rounding/contraction barrier
    return r;
}
__device__ __forceinline__ float mulb(float a, float b) { return fbar(a * b); }

// Face record (14 used floats @ stride 17):
// [0..5] v0x v0y v1x v1y v2x v2y, [6] inv_area,
// [7..12] uv0x uv0y uv1x uv1y uv2x uv2y
__global__ __launch_bounds__(256)
void wm_fused(const float* __restrict__ points,
              const float* __restrict__ uvp,
              const int*   __restrict__ faces,
              int nf, int np,
              const float* __restrict__ img,
              float* __restrict__ out)
{
    __shared__ float vx[NP_MAX], vy[NP_MAX], tux[NP_MAX], tuy[NP_MAX];
    __shared__ float flds[NF_MAX * FSTRIDE];
    __shared__ unsigned long long masks[8];
    __shared__ int   list[NF_MAX];

    const int tid = threadIdx.x;
    const float sc = (float)(383.0 / 384.0);  // (W-1)/W rounded to fp32

    // ---- vertex stage: coalesced loads, 4 IEEE divides per vertex ----
    if (tid < np) {
        float px = points[tid*2 + 0];
        float py = points[tid*2 + 1];
        vx[tid]  = fbar(fbar(fbar(px / 383.0f) * 2.0f - 1.0f) * sc);
        vy[tid]  = fbar(fbar(fbar(py / 383.0f) * 2.0f - 1.0f) * sc);
        tux[tid] = fbar(uvp[tid*2 + 0] / 383.0f);
        tuy[tid] = fbar(uvp[tid*2 + 1] / 383.0f);
    }
    __syncthreads();

    // ---- tile NDC bounds + margin ----
    const int lx = tid & 15, ly = tid >> 4;
    const int c0 = blockIdx.x * 16, r0 = blockIdx.y * 16;
    const int col = c0 + lx, row = r0 + ly;

    const float tx_lo = 2.0f * ((float)c0 + 0.5f)  / 384.0f - 1.0f - MARGIN;
    const float tx_hi = 2.0f * ((float)c0 + 15.5f) / 384.0f - 1.0f + MARGIN;
    const float ty_lo = 2.0f * ((float)r0 + 0.5f)  / 384.0f - 1.0f - MARGIN;
    const float ty_hi = 2.0f * ((float)r0 + 15.5f) / 384.0f - 1.0f + MARGIN;

    // ---- face stage fused with bbox test + ballot (2 uniform rounds) ----
    bool pred[2];
    #pragma unroll
    for (int r = 0; r < 2; ++r) {
        const int f = r * 256 + tid;
        bool p = false;
        if (f < nf) {
            int i0 = faces[f*3 + 0];
            int i1 = faces[f*3 + 1];
            int i2 = faces[f*3 + 2];

            float v0x = vx[i0], v0y = vy[i0];
            float v1x = vx[i1], v1y = vy[i1];
            float v2x = vx[i2], v2y = vy[i2];

            // area = (v1x-v0x)*(v2y-v0y) - (v1y-v0y)*(v2x-v0x), no contraction
            float area = fbar(mulb(v1x - v0x, v2y - v0y)
                            - mulb(v1y - v0y, v2x - v0x));
            bool  valid    = (fabsf(area) >= 1e-8f);
            float inv_area = fbar(1.0f / (valid ? area : 1.0f));

            float* o = &flds[f * FSTRIDE];
            o[0] = v0x; o[1] = v0y; o[2] = v1x; o[3] = v1y;
            o[4] = v2x; o[5] = v2y; o[6] = inv_area;
            o[7]  = tux[i0]; o[8]  = tuy[i0];
            o[9]  = tux[i1]; o[10] = tuy[i1];
            o[11] = tux[i2]; o[12] = tuy[i2];

            if (valid) {
                float bxmin = fminf(fminf(v0x, v1x), v2x);
                float bymin = fminf(fminf(v0y, v1y), v2y);
                float bxmax = fmaxf(fmaxf(v0x, v1x), v2x);
                float bymax = fmaxf(fmaxf(v0y, v1y), v2y);
                p = (bxmin <= tx_hi) & (bxmax >= tx_lo)
                  & (bymin <= ty_hi) & (bymax >= ty_lo);
            }
        }
        pred[r] = p;
        unsigned long long m = __ballot(p);   // uniform: all lanes execute
        if ((tid & 63) == 0) masks[r * 4 + (tid >> 6)] = m;
    }
    __syncthreads();   // covers flds writes + masks

    int ncand = 0;
    #pragma unroll
    for (int k = 0; k < 8; ++k) ncand += __popcll(masks[k]);

    const int lane = tid & 63;
    const unsigned long long below = (lane == 0) ? 0ULL : ((1ULL << lane) - 1ULL);
    #pragma unroll
    for (int r = 0; r < 2; ++r) {
        if (pred[r]) {
            int w = r * 4 + (tid >> 6);
            int pos = __popcll(masks[w] & below);
            for (int k = 0; k < w; ++k) pos += __popcll(masks[k]);
            list[pos] = r * 256 + tid;
        }
    }
    __syncthreads();

    // ---- per-pixel raster over candidates (ascending face order) ----
    const float px = fbar(fbar(2.0f * ((float)col + 0.5f) / 384.0f) - 1.0f);
    const float py = fbar(fbar(2.0f * ((float)row + 0.5f) / 384.0f) - 1.0f);

    int   hitoff = -1;
    float b0 = 0.0f, b1 = 0.0f, b2 = 0.0f;

    for (int i = 0; i < ncand; ++i) {
        const float* fd = &flds[list[i] * FSTRIDE];  // broadcast LDS reads
        const float v0x = fd[0], v0y = fd[1];
        const float v1x = fd[2], v1y = fd[3];
        const float v2x = fd[4], v2y = fd[5];
        const float ia  = fd[6];

        // edge_fn(a,b) = (bx-ax)*(py-ay) - (by-ay)*(px-ax), no contraction
        float e0 = fbar(mulb(v2x - v1x, py - v1y) - mulb(v2y - v1y, px - v1x));
        float e1 = fbar(mulb(v0x - v2x, py - v2y) - mulb(v0y - v2y, px - v2x));
        float e2 = fbar(mulb(v1x - v0x, py - v0y) - mulb(v1y - v0y, px - v0x));

        float w0 = mulb(e0, ia);
        float w1 = mulb(e1, ia);
        float w2 = mulb(e2, ia);

        if (w0 >= -1e-7f && w1 >= -1e-7f && w2 >= -1e-7f) {
            hitoff = list[i] * FSTRIDE; b0 = w0; b1 = w1; b2 = w2;
            break;  // ascending order -> first hit == argmax(inside)
        }
    }

    float c0f = 0.0f, c1f = 0.0f, c2f = 0.0f;
    if (hitoff >= 0) {
        const float* fd = &flds[hitoff];
        float ux = b0 * fd[7] + b1 * fd[9]  + b2 * fd[11];
        float uy = b0 * fd[8] + b1 * fd[10] + b2 * fd[12];

        float x = fminf(fmaxf(ux * 383.0f, 0.0f), 383.0f);
        float y = fminf(fmaxf(uy * 383.0f, 0.0f), 383.0f);
        int x0 = (int)floorf(x);
        int y0 = (int)floorf(y);
        int x1 = min(x0 + 1, 383);
        int y1 = min(y0 + 1, 383);
        float fx = x - (float)x0;
        float fy = y - (float)y0;

        const float* p00 = &img[(y0 * WIMG + x0) * 3];
        const float* p10 = &img[(y0 * WIMG + x1) * 3];
        const float* p01 = &img[(y1 * WIMG + x0) * 3];
        const float* p11 = &img[(y1 * WIMG + x1) * 3];

        float w00 = (1.0f - fx) * (1.0f - fy);
        float w10 = fx * (1.0f - fy);
        float w01 = (1.0f - fx) * fy;
        float w11 = fx * fy;

        c0f = p00[0]*w00 + p10[0]*w10 + p01[0]*w01 + p11[0]*w11;
        c1f = p00[1]*w00 + p10[1]*w10 + p01[1]*w01 + p11[1]*w11;
        c2f = p00[2]*w00 + p10[2]*w10 + p01[2]*w01 + p11[2]*w11;
    }

    const int p = row * WIMG + col;
    out[p * 3 + 0] = c0f;
    out[p * 3 + 1] = c1f;
    out[p * 3 + 2] = c2f;
}

extern "C" void kernel_launch(void* const* d_in, const int* in_sizes, int n_in,
                              void* d_out, int out_size, void* d_ws, size_t ws_size,
                              hipStream_t stream) {
    const float* points = (const float*)d_in[0];
    const float* uvp    = (const float*)d_in[1];
    const float* img    = (const float*)d_in[2];
    const int*   faces  = (const int*)d_in[3];

    int nf = in_sizes[3] / 3;
    if (nf > NF_MAX) nf = NF_MAX;
    int np = in_sizes[0] / 2;
    if (np > NP_MAX) np = NP_MAX;

    hipLaunchKernelGGL(wm_fused, dim3(WIMG / 16, HIMG / 16), dim3(256), 0, stream,
                       points, uvp, faces, nf, np, img, (float*)d_out);
}